// Round 19
// baseline (131.160 us; speedup 1.0000x reference)
//
#include <hip/hip_runtime.h>

#define B_DIM   2
#define S_DIM   2048
#define D_DIM   1024
#define N_HEADS 16
#define H_DIM   64
#define NH      1024
#define M_DIM   4096   // B * S

typedef short bf16x8 __attribute__((ext_vector_type(8)));
typedef short bf16x4 __attribute__((ext_vector_type(4)));
typedef float f32x4  __attribute__((ext_vector_type(4)));

// 1/sqrt(64) * log2(e) folded into Q: attention uses raw v_exp_f32 (2^x).
#define QSCALE (0.125f * 1.44269504088896f)

__device__ __forceinline__ short f2bf(float x) {
    unsigned u = __float_as_uint(x);
    u = (u + 0x7fffu + ((u >> 16) & 1u)) >> 16;   // RNE
    return (short)u;
}

__device__ __forceinline__ void glds16(const void* g, void* l) {
    __builtin_amdgcn_global_load_lds(
        (const __attribute__((address_space(1))) unsigned int*)g,
        (__attribute__((address_space(3))) unsigned int*)l, 16, 0, 0);
}

#define VMCNT(n) asm volatile("s_waitcnt vmcnt(" #n ")" ::: "memory")

// ---------------------------------------------------------------------------
// Fused prep (r11/r13-proven, byte-identical to r17).
// ---------------------------------------------------------------------------
#define CVT_BLOCKS 8192
#define WT_BLOCKS  768
#define MP_BLOCKS  1024

__global__ __launch_bounds__(256)
void prep_fused(const float* __restrict__ fa, const float* __restrict__ fb,
                short* __restrict__ da, short* __restrict__ db,
                const float* __restrict__ wq, const float* __restrict__ wk,
                const float* __restrict__ wv, short* __restrict__ Wt,
                const int* __restrict__ mask,
                unsigned long long* __restrict__ mp)
{
    __shared__ short T[64][66];      // used only by the wtrans role
    const int bid = blockIdx.x;
    const int tid = threadIdx.x;

    if (bid < CVT_BLOCKS) {
        const int n4 = (M_DIM * D_DIM) / 4;
        int i = bid * 256 + tid;
        const float* s = (i < n4) ? fa : fb;
        short* d = (i < n4) ? da : db;
        int j = (i < n4) ? i : i - n4;
        float4 v = ((const float4*)s)[j];
        bf16x4 o;
        o[0] = f2bf(v.x); o[1] = f2bf(v.y); o[2] = f2bf(v.z); o[3] = f2bf(v.w);
        ((bf16x4*)d)[j] = o;
        return;
    }

    if (bid < CVT_BLOCKS + WT_BLOCKS) {
        const int idx = bid - CVT_BLOCKS;
        const int z = idx >> 8;                 // weight select
        const int r = idx & 255;
        const int d0 = (r & 15) * 64, n0 = (r >> 4) * 64;
        const float* W = (z == 0) ? wq : (z == 1) ? wk : wv;
        short* dst = Wt + (size_t)z * NH * D_DIM;
        {
            const int dr = tid >> 2, nc = (tid & 3) * 16;
            const float* src = &W[(size_t)(d0 + dr) * NH + n0 + nc];
            float vv[16];
            #pragma unroll
            for (int q = 0; q < 4; ++q) {
                float4 v = ((const float4*)src)[q];
                vv[q*4+0] = v.x; vv[q*4+1] = v.y; vv[q*4+2] = v.z; vv[q*4+3] = v.w;
            }
            #pragma unroll
            for (int j = 0; j < 16; ++j) T[nc + j][dr] = f2bf(vv[j]);
        }
        __syncthreads();
        {
            const int nr = tid >> 2, dc = (tid & 3) * 16;
            short o[16];
            #pragma unroll
            for (int j = 0; j < 16; ++j) o[j] = T[nr][dc + j];
            short* dstp = &dst[(size_t)(n0 + nr) * D_DIM + d0 + dc];
            *(bf16x8*)(dstp)     = *(bf16x8*)&o[0];
            *(bf16x8*)(dstp + 8) = *(bf16x8*)&o[8];
        }
        return;
    }

    {
        const int lane = tid & 63;
        const int wid  = ((bid - CVT_BLOCKS - WT_BLOCKS) * 256 + tid) >> 6;
        const int nw   = (MP_BLOCKS * 256) >> 6;            // 4096 waves
        const int total = B_DIM * S_DIM * (S_DIM / 64);     // 131072
        for (int idx = wid; idx < total; idx += nw) {
            int m = mask[(size_t)idx * 64 + lane];
            unsigned long long bits = __ballot(m != 0);
            if (lane == 0) mp[idx] = bits;
        }
    }
}

// ---------------------------------------------------------------------------
// Fused QKV projection v19 (= v18 with corrected staging bases): 128x64
// tiles, grid 1536 x 256 threads (4 waves, 2x2 wave grid, per-wave 64x32,
// acc[4][2]). LDS 24KB (2 buffers x (A 8KB + B 4KB)) -> 6 blocks/CU.
// Staging bases: wave w writes 512 shorts (16 rows x 32) at w*512 (r17's
// proven arithmetic; r18's w*256 overlapped waves -> NaN).
// 1-deep counted prefetch VMCNT(3); bijective XCD swizzle (1536 = 8 x 192).
// ---------------------------------------------------------------------------
__global__ __launch_bounds__(256)
void proj_mfma(const short* __restrict__ Fb, const short* __restrict__ Tb_,
               const short* __restrict__ Wt,
               const float* __restrict__ bq, const float* __restrict__ bk,
               const float* __restrict__ bv,
               short* __restrict__ Qo, short* __restrict__ Ko,
               short* __restrict__ Vo)
{
    __shared__ short SH[12288];   // 24 KB: Al[2][4096] | Bl[2][2048]
    short* AlS = SH;              // A: 128 rows x 32 shorts per buffer
    short* BlS = SH + 8192;       // B:  64 rows x 32 shorts per buffer

    const int tid  = threadIdx.x;
    const int lane = tid & 63, w = tid >> 6;       // w in [0,4)
    const int g = lane >> 4, l15 = lane & 15;
    const int wm = w >> 1, wn = w & 1;             // 2 x 2 wave grid

    // XCD swizzle: bid%8 = XCD; bx = (bid&7) + 8*(q/48), by = q%48 (bijective)
    const int bid = blockIdx.x;
    const int q  = bid >> 3;
    const int bx = (bid & 7) + 8 * (q / 48);       // [0,32) A-row panel
    const int by = q % 48;                         // [0,48) 64-col W panel

    const int row0 = bx * 128;
    const int region = by >> 4;                    // 0=Q 1=K 2=V
    const short* X = (region == 0) ? Fb : Tb_;

    // staging: 16 rows (512 shorts) per wave per glds; A = 2 calls, B = 1.
    const int cl8   = ((lane & 3) ^ ((lane >> 3) & 3)) * 8;
    const size_t off0 = (size_t)(w * 16 + (lane >> 2)) * D_DIM + cl8;
    const size_t offA1 = off0 + 64 * D_DIM;
    const short* Abase = X + (size_t)row0 * D_DIM;
    const short* Bbase = Wt + (size_t)by * 64 * D_DIM;

    const int swz3 = (l15 >> 1) & 3;

    f32x4 acc[4][2];
    #pragma unroll
    for (int i = 0; i < 4; ++i)
        #pragma unroll
        for (int j = 0; j < 2; ++j)
            acc[i][j] = (f32x4){0.f, 0.f, 0.f, 0.f};

    // prologue: stage k-tile 0 into buffer 0 (A0 rows 0-63, A1 rows 64-127, B)
    glds16(Abase + off0,  AlS + 0*4096 + w*512);
    glds16(Abase + offA1, AlS + 0*4096 + 2048 + w*512);
    glds16(Bbase + off0,  BlS + 0*2048 + w*512);

    const char* AlC = (const char*)AlS;
    const char* BlC = (const char*)BlS;

    for (int kt = 0; kt < 32; ++kt) {
        const int cur = kt & 1;
        if (kt < 31) {
            const int k1 = (kt + 1) * 32;
            glds16(Abase + k1 + off0,  AlS + (cur^1)*4096 + w*512);
            glds16(Abase + k1 + offA1, AlS + (cur^1)*4096 + 2048 + w*512);
            glds16(Bbase + k1 + off0,  BlS + (cur^1)*2048 + w*512);
            VMCNT(3);            // retire tile kt; kt+1's 3 stay in flight
        } else {
            VMCNT(0);
        }
        __builtin_amdgcn_s_barrier();
        __builtin_amdgcn_sched_barrier(0);

        const int cbA = cur * 8192;   // byte offsets of compute buffers
        const int cbB = cur * 4096;
        bf16x8 af[4], bfr[2];
        #pragma unroll
        for (int mb = 0; mb < 4; ++mb)
            af[mb] = *(const bf16x8*)
                (AlC + cbA + ((wm*64 + mb*16 + l15)*32 + (g ^ swz3)*8) * 2);
        #pragma unroll
        for (int nb = 0; nb < 2; ++nb)
            bfr[nb] = *(const bf16x8*)
                (BlC + cbB + ((wn*32 + nb*16 + l15)*32 + (g ^ swz3)*8) * 2);
        #pragma unroll
        for (int mb = 0; mb < 4; ++mb)
            #pragma unroll
            for (int nb = 0; nb < 2; ++nb)
                acc[mb][nb] = __builtin_amdgcn_mfma_f32_16x16x32_bf16(
                    af[mb], bfr[nb], acc[mb][nb], 0, 0, 0);
        __builtin_amdgcn_sched_barrier(0);
        __builtin_amdgcn_s_barrier();
    }

    const float* bias = (region == 0) ? bq : (region == 1) ? bk : bv;
    const float scale = (region == 0) ? QSCALE : 1.0f;
    const int colL0 = (by & 15) * 64 + wn * 32;

    if (region < 2) {
        // per-wave bounce buffer overlays the (dead) staging LDS
        short* Ttw = SH + w * 320;    // [16][20] shorts per wave
        short* Out = (region == 0) ? Qo : Ko;
        #pragma unroll
        for (int mb = 0; mb < 4; ++mb)
            #pragma unroll
            for (int nb = 0; nb < 2; ++nb) {
                const float bvv = bias[colL0 + nb*16 + l15];
                #pragma unroll
                for (int r = 0; r < 4; ++r)
                    Ttw[(4*g + r)*20 + l15] = f2bf((acc[mb][nb][r] + bvv) * scale);
                bf16x4 t4 = *(const bf16x4*)&Ttw[l15*20 + 4*g];
                const int sg  = row0 + wm*64 + mb*16 + l15;
                const int bb  = sg >> 11, s = sg & 2047;
                const int cg  = colL0 + nb*16 + 4*g;
                const int n   = cg >> 6, hh = cg & 63;
                *(bf16x4*)&Out[(((size_t)(bb*N_HEADS + n)*S_DIM + s) << 6) + hh] = t4;
            }
    } else {
        #pragma unroll
        for (int mb = 0; mb < 4; ++mb)
            #pragma unroll
            for (int nb = 0; nb < 2; ++nb) {
                const int nhv = colL0 + nb*16 + l15;
                const float bvv = bias[nhv];
                bf16x4 t4;
                #pragma unroll
                for (int r = 0; r < 4; ++r)
                    t4[r] = f2bf(acc[mb][nb][r] + bvv);
                const int s4 = row0 + wm*64 + mb*16 + 4*g;
                const int bb = s4 >> 11, s = s4 & 2047;
                *(bf16x4*)&Vo[((size_t)(bb*NH + nhv) << 11) + s] = t4;
            }
    }
}

// ---------------------------------------------------------------------------
// Flash attention (r15/r16/r17-exact, passing): r13 all-MFMA32 + T15
// cross-tile pipeline (softmax(tt-1) -> QK(tt) -> PV(tt-1), 3 V slots).
// ---------------------------------------------------------------------------
__global__ __launch_bounds__(256)
void attn_mfma(const short* __restrict__ Qb, const short* __restrict__ Kb,
               const short* __restrict__ Vt,
               const unsigned long long* __restrict__ mp,
               float* __restrict__ out)
{
    __shared__ short Kl[2][4096];   // [buf][staged t-row * 64 + swizzled chunk]
    __shared__ short Vl[3][4096];   // [slot][h-row * 64 + swizzled chunk]

    const int tid  = threadIdx.x;
    const int lane = tid & 63, w = tid >> 6;
    const int g = lane >> 4, l15 = lane & 15;

    // XCD swizzle: each XCD gets 128 consecutive logical blocks = 4 heads
    const int lin = (blockIdx.x & 7) * 128 + (blockIdx.x >> 3);
    const int f0 = (lin & 31) << 6;
    const int n  = (lin >> 5) & 15;
    const int b  = lin >> 9;

    const short* Qbase = Qb + (size_t)(b*N_HEADS + n) * S_DIM * H_DIM;
    const short* Kbase = Kb + (size_t)(b*N_HEADS + n) * S_DIM * H_DIM;
    const short* Vbase = Vt + (size_t)(b*NH + n*H_DIM) * S_DIM;

    const int frow = f0 + w*16 + l15;        // this lane's f (fragment col)

    bf16x8 qf[2];
    #pragma unroll
    for (int hc = 0; hc < 2; ++hc)
        qf[hc] = *(const bf16x8*)&Qbase[(size_t)frow * H_DIM + hc*32 + 8*g];

    // ---- K staging with row permutation (r13-exact) ----
    const int e   = lane >> 3;               // staged row within 8-group
    const int cl8 = ((lane & 7) ^ e) * 8;    // chunk swizzle (key = s&7 = e)
    const int s32_0 = (w & 1) * 16 + e;      // staged local row, glds call 0
    const int s32_1 = s32_0 + 8;             //                  glds call 1
    const int i0 = s32_0 & 15, i1 = s32_1 & 15;
    const int t0loc = 8*(i0 >> 2) + (i0 & 3) + ((s32_0 >> 4) ? 4 : 0);
    const int t1loc = 8*(i1 >> 2) + (i1 & 3) + ((s32_1 >> 4) ? 4 : 0);
    const int grpw  = w >> 1;                // which 32-row group this wave stages
    const size_t kOff0 = (size_t)(grpw*32 + t0loc) * H_DIM + cl8;
    const size_t kOff1 = (size_t)(grpw*32 + t1loc) * H_DIM + cl8;
    // V staging: linear rows (h), r13-exact
    const int rk  = w * 16 + e;
    const size_t vOff0 = (size_t)rk * S_DIM + cl8;
    const size_t vOff1 = vOff0 + 8 * S_DIM;

    const unsigned long long* mrp = mp + ((size_t)(b*S_DIM + frow) << 5);

    const int swz7 = l15 & 7;
    const int g8 = 8 * g;
    const bf16x8 ones8 = {0x3F80, 0x3F80, 0x3F80, 0x3F80,
                          0x3F80, 0x3F80, 0x3F80, 0x3F80};

    // fragment byte-offsets (constant across t-loop; r13-exact)
    int koffA[4], koffB[4], voff32[2][4];
    #pragma unroll
    for (int tb = 0; tb < 4; ++tb) {
        koffA[tb] = ((tb*16 + l15)*64 + ((g    ) ^ swz7)*8) * 2;
        koffB[tb] = ((tb*16 + l15)*64 + ((4 + g) ^ swz7)*8) * 2;
    }
    #pragma unroll
    for (int grp = 0; grp < 2; ++grp)
        #pragma unroll
        for (int hb = 0; hb < 4; ++hb)
            voff32[grp][hb] = ((hb*16 + l15)*64 + ((grp*4 + g) ^ swz7)*8) * 2;

    f32x4 o2[4];     // O^T: row h = hb*16 + 4g + r, col f = l15
    f32x4 lacc;      // denominator (all rows equal)
    #pragma unroll
    for (int hb = 0; hb < 4; ++hb) o2[hb] = (f32x4){0.f, 0.f, 0.f, 0.f};
    lacc = (f32x4){0.f, 0.f, 0.f, 0.f};

    short* VlF = &Vl[0][0];

    // prologue: tile 0 -> K buf 0, V slot 0
    glds16(Kbase + kOff0, &Kl[0][w * 1024]);
    glds16(Kbase + kOff1, &Kl[0][w * 1024 + 512]);
    glds16(Vbase + vOff0, &VlF[0*4096 + w * 1024]);
    glds16(Vbase + vOff1, &VlF[0*4096 + w * 1024 + 512]);

    const char* KlB = (const char*)&Kl[0][0];
    const char* VlB = (const char*)&Vl[0][0];

    f32x4 sv[4];
    #pragma unroll
    for (int tb = 0; tb < 4; ++tb) sv[tb] = (f32x4){0.f, 0.f, 0.f, 0.f};
    unsigned long long mkP = 0, mkC = 0;
    int vsP = 2, vsC = 0, vsF = 1;   // prev / current / free(stage target)

    for (int tt = 0; tt <= 32; ++tt) {
        const int cur = tt & 1;
        const int cb  = cur << 13;           // K buffer byte offset

        if (tt < 32) mkC = mrp[tt];
        __builtin_amdgcn_sched_barrier(0);

        if (tt < 31) {
            const int t1 = (tt + 1) * 64;
            glds16(Kbase + (size_t)t1*H_DIM + kOff0, &Kl[cur^1][w*1024]);
            glds16(Kbase + (size_t)t1*H_DIM + kOff1, &Kl[cur^1][w*1024 + 512]);
            glds16(Vbase + t1 + vOff0, &VlF[vsF*4096 + w*1024]);
            glds16(Vbase + t1 + vOff1, &VlF[vsF*4096 + w*1024 + 512]);
            VMCNT(4);
        } else if (tt == 31) {
            VMCNT(0);
        }
        if (tt < 32) {
            __builtin_amdgcn_s_barrier();
            __builtin_amdgcn_sched_barrier(0);   // pin LDS reads after barrier
        }

        // ---- phase 1: softmax of tile tt-1 (consumes sv, mkP) ----
        bf16x8 P32g[2];
        if (tt > 0) {
            #pragma unroll
            for (int grp = 0; grp < 2; ++grp) {
                const f32x4 svA = sv[2*grp];       // t = grp*32 + 8g + r
                const f32x4 svB = sv[2*grp + 1];   // t = grp*32 + 8g + 4 + r
                const unsigned mbyte = (unsigned)(mkP >> (grp*32 + g8));
                float pA0 = (mbyte &   1u) ? __builtin_amdgcn_exp2f(svA[0]) : 0.f;
                float pA1 = (mbyte &   2u) ? __builtin_amdgcn_exp2f(svA[1]) : 0.f;
                float pA2 = (mbyte &   4u) ? __builtin_amdgcn_exp2f(svA[2]) : 0.f;
                float pA3 = (mbyte &   8u) ? __builtin_amdgcn_exp2f(svA[3]) : 0.f;
                float pB0 = (mbyte &  16u) ? __builtin_amdgcn_exp2f(svB[0]) : 0.f;
                float pB1 = (mbyte &  32u) ? __builtin_amdgcn_exp2f(svB[1]) : 0.f;
                float pB2 = (mbyte &  64u) ? __builtin_amdgcn_exp2f(svB[2]) : 0.f;
                float pB3 = (mbyte & 128u) ? __builtin_amdgcn_exp2f(svB[3]) : 0.f;
                unsigned u0, u1, u2, u3;
                asm("v_cvt_pk_bf16_f32 %0, %1, %2" : "=v"(u0) : "v"(pA0), "v"(pA1));
                asm("v_cvt_pk_bf16_f32 %0, %1, %2" : "=v"(u1) : "v"(pA2), "v"(pA3));
                asm("v_cvt_pk_bf16_f32 %0, %1, %2" : "=v"(u2) : "v"(pB0), "v"(pB1));
                asm("v_cvt_pk_bf16_f32 %0, %1, %2" : "=v"(u3) : "v"(pB2), "v"(pB3));
                union { unsigned u[4]; bf16x8 v; } pk;
                pk.u[0] = u0; pk.u[1] = u1; pk.u[2] = u2; pk.u[3] = u3;
                P32g[grp] = pk.v;                  // k = 8g + {0..7}
            }
        }

        // ---- phase 2: QK(tt) refills sv in place ----
        if (tt < 32) {
            #pragma unroll
            for (int tb = 0; tb < 4; ++tb) {
                bf16x8 kf0 = *(const bf16x8*)(KlB + cb + koffA[tb]);
                bf16x8 kf1 = *(const bf16x8*)(KlB + cb + koffB[tb]);
                const f32x4 z = (f32x4){0.f, 0.f, 0.f, 0.f};
                sv[tb] = __builtin_amdgcn_mfma_f32_16x16x32_bf16(kf0, qf[0], z, 0, 0, 0);
                sv[tb] = __builtin_amdgcn_mfma_f32_16x16x32_bf16(kf1, qf[1], sv[tb], 0, 0, 0);
            }
        }

        // ---- phase 3: PV(tile tt-1) from V slot vsP ----
        if (tt > 0) {
            const int vb = vsP * 8192;   // V slot byte offset
            #pragma unroll
            for (int grp = 0; grp < 2; ++grp) {
                #pragma unroll
                for (int hb = 0; hb < 4; ++hb) {
                    bf16x8 va = *(const bf16x8*)(VlB + vb + voff32[grp][hb]);
                    o2[hb] = __builtin_amdgcn_mfma_f32_16x16x32_bf16(
                        va, P32g[grp], o2[hb], 0, 0, 0);
                }
                lacc = __builtin_amdgcn_mfma_f32_16x16x32_bf16(
                    ones8, P32g[grp], lacc, 0, 0, 0);
            }
        }

        __builtin_amdgcn_sched_barrier(0);   // pin reads BEFORE exit barrier
        if (tt < 32) __builtin_amdgcn_s_barrier();

        mkP = mkC;
        const int t_ = vsP; vsP = vsC; vsC = vsF; vsF = t_;
    }

    // ---- epilogue: normalize lane-locally, store f32x4 per (f, h-quad) ----
    {
        const float inv = 1.0f / lacc[0];
        float* orow = &out[((size_t)(b*S_DIM + frow) << 10) + (n << 6) + 4*g];
        #pragma unroll
        for (int hb = 0; hb < 4; ++hb) {
            f32x4 v = o2[hb] * inv;
            *(f32x4*)&orow[hb*16] = v;
        }
    }
}

extern "C" void kernel_launch(void* const* d_in, const int* in_sizes, int n_in,
                              void* d_out, int out_size, void* d_ws, size_t ws_size,
                              hipStream_t stream)
{
    const float* from = (const float*)d_in[0];
    const float* to   = (const float*)d_in[1];
    const int*   mask = (const int*)d_in[2];
    const float* wq   = (const float*)d_in[3];
    const float* bq   = (const float*)d_in[4];
    const float* wk   = (const float*)d_in[5];
    const float* bk   = (const float*)d_in[6];
    const float* wv   = (const float*)d_in[7];
    const float* bv   = (const float*)d_in[8];
    float* out = (float*)d_out;

    char* p = (char*)d_ws;
    const size_t sz_x   = (size_t)M_DIM * D_DIM * 2;
    const size_t sz_w   = (size_t)NH * D_DIM * 2;
    const size_t sz_qkv = (size_t)B_DIM * N_HEADS * S_DIM * H_DIM * 2;
    short* Fb  = (short*)p;            p += sz_x;
    short* Tbf = (short*)p;            p += sz_x;
    short* Wts = (short*)p;            p += 3 * sz_w;   // Q|K|V stacked
    short* Qw  = (short*)p;            p += sz_qkv;
    short* Kw  = (short*)p;            p += sz_qkv;
    short* Vw  = (short*)p;            p += sz_qkv;
    unsigned long long* mpk = (unsigned long long*)p;   // 1,048,576 B

    prep_fused<<<CVT_BLOCKS + WT_BLOCKS + MP_BLOCKS, 256, 0, stream>>>(
        from, to, Fb, Tbf, wq, wk, wv, Wts, mask, mpk);

    proj_mfma<<<1536, 256, 0, stream>>>(Fb, Tbf, Wts, bq, bk, bv, Qw, Kw, Vw);

    attn_mfma<<<1024, 256, 0, stream>>>(Qw, Kw, Vw, mpk, out);
}

// Round 20
// 119.091 us; speedup vs baseline: 1.1013x; 1.1013x over previous
//
#include <hip/hip_runtime.h>

#define B_DIM   2
#define S_DIM   2048
#define D_DIM   1024
#define N_HEADS 16
#define H_DIM   64
#define NH      1024
#define M_DIM   4096   // B * S

typedef short bf16x8 __attribute__((ext_vector_type(8)));
typedef short bf16x4 __attribute__((ext_vector_type(4)));
typedef float f32x4  __attribute__((ext_vector_type(4)));

// 1/sqrt(64) * log2(e) folded into Q: attention uses raw v_exp_f32 (2^x).
#define QSCALE (0.125f * 1.44269504088896f)

__device__ __forceinline__ short f2bf(float x) {
    unsigned u = __float_as_uint(x);
    u = (u + 0x7fffu + ((u >> 16) & 1u)) >> 16;   // RNE
    return (short)u;
}

__device__ __forceinline__ void glds16(const void* g, void* l) {
    __builtin_amdgcn_global_load_lds(
        (const __attribute__((address_space(1))) unsigned int*)g,
        (__attribute__((address_space(3))) unsigned int*)l, 16, 0, 0);
}

#define VMCNT(n) asm volatile("s_waitcnt vmcnt(" #n ")" ::: "memory")

// ---------------------------------------------------------------------------
// Fused prep (r11/r13-proven, byte-identical to r17).
// ---------------------------------------------------------------------------
#define CVT_BLOCKS 8192
#define WT_BLOCKS  768
#define MP_BLOCKS  1024

__global__ __launch_bounds__(256)
void prep_fused(const float* __restrict__ fa, const float* __restrict__ fb,
                short* __restrict__ da, short* __restrict__ db,
                const float* __restrict__ wq, const float* __restrict__ wk,
                const float* __restrict__ wv, short* __restrict__ Wt,
                const int* __restrict__ mask,
                unsigned long long* __restrict__ mp)
{
    __shared__ short T[64][66];      // used only by the wtrans role
    const int bid = blockIdx.x;
    const int tid = threadIdx.x;

    if (bid < CVT_BLOCKS) {
        const int n4 = (M_DIM * D_DIM) / 4;
        int i = bid * 256 + tid;
        const float* s = (i < n4) ? fa : fb;
        short* d = (i < n4) ? da : db;
        int j = (i < n4) ? i : i - n4;
        float4 v = ((const float4*)s)[j];
        bf16x4 o;
        o[0] = f2bf(v.x); o[1] = f2bf(v.y); o[2] = f2bf(v.z); o[3] = f2bf(v.w);
        ((bf16x4*)d)[j] = o;
        return;
    }

    if (bid < CVT_BLOCKS + WT_BLOCKS) {
        const int idx = bid - CVT_BLOCKS;
        const int z = idx >> 8;                 // weight select
        const int r = idx & 255;
        const int d0 = (r & 15) * 64, n0 = (r >> 4) * 64;
        const float* W = (z == 0) ? wq : (z == 1) ? wk : wv;
        short* dst = Wt + (size_t)z * NH * D_DIM;
        {
            const int dr = tid >> 2, nc = (tid & 3) * 16;
            const float* src = &W[(size_t)(d0 + dr) * NH + n0 + nc];
            float vv[16];
            #pragma unroll
            for (int q = 0; q < 4; ++q) {
                float4 v = ((const float4*)src)[q];
                vv[q*4+0] = v.x; vv[q*4+1] = v.y; vv[q*4+2] = v.z; vv[q*4+3] = v.w;
            }
            #pragma unroll
            for (int j = 0; j < 16; ++j) T[nc + j][dr] = f2bf(vv[j]);
        }
        __syncthreads();
        {
            const int nr = tid >> 2, dc = (tid & 3) * 16;
            short o[16];
            #pragma unroll
            for (int j = 0; j < 16; ++j) o[j] = T[nr][dc + j];
            short* dstp = &dst[(size_t)(n0 + nr) * D_DIM + d0 + dc];
            *(bf16x8*)(dstp)     = *(bf16x8*)&o[0];
            *(bf16x8*)(dstp + 8) = *(bf16x8*)&o[8];
        }
        return;
    }

    {
        const int lane = tid & 63;
        const int wid  = ((bid - CVT_BLOCKS - WT_BLOCKS) * 256 + tid) >> 6;
        const int nw   = (MP_BLOCKS * 256) >> 6;            // 4096 waves
        const int total = B_DIM * S_DIM * (S_DIM / 64);     // 131072
        for (int idx = wid; idx < total; idx += nw) {
            int m = mask[(size_t)idx * 64 + lane];
            unsigned long long bits = __ballot(m != 0);
            if (lane == 0) mp[idx] = bits;
        }
    }
}

// ---------------------------------------------------------------------------
// Fused QKV projection (r17-exact, proven 45us): 512 threads / 8 waves per
// block (2x4 wave grid, 64x32 subtile each, acc[4][2]). Per wave per tile:
// 1 A-glds + 1 B-glds. 3-buffer 2-deep prefetch, counted VMCNT(4);
// XCD swizzle. LDS 48KB -> 3 blocks/CU (24 waves/CU).
// ---------------------------------------------------------------------------
__global__ __launch_bounds__(512, 6)
void proj_mfma(const short* __restrict__ Fb, const short* __restrict__ Tb_,
               const short* __restrict__ Wt,
               const float* __restrict__ bq, const float* __restrict__ bk,
               const float* __restrict__ bv,
               short* __restrict__ Qo, short* __restrict__ Ko,
               short* __restrict__ Vo)
{
    __shared__ short SH[24576];   // 48 KB: Al[3][4096] | Bl[3][4096]
    short* AlS = SH;
    short* BlS = SH + 12288;

    const int tid  = threadIdx.x;
    const int lane = tid & 63, w = tid >> 6;       // w in [0,8)
    const int g = lane >> 4, l15 = lane & 15;
    const int wm = w >> 2, wn = w & 3;             // 2 x 4 wave grid

    // XCD swizzle (r16-exact): bid%8 groups same-A-panel blocks on one XCD
    const int bid = blockIdx.x;
    const int q  = bid >> 3;
    const int bx = (bid & 7) + 8 * (q / 24);       // [0,32) A-row panel
    const int by = q % 24;                         // [0,24) W panel / region

    const int row0 = bx * 128;
    const int region = by >> 3;                    // 0=Q 1=K 2=V
    const short* X = (region == 0) ? Fb : Tb_;

    // staging: wave w stages A rows [w*16, w*16+16) and B rows likewise,
    // one glds each. lane -> row w*16 + (lane>>2), chunk (lane&3)^((lane>>3)&3)
    const int cl8   = ((lane & 3) ^ ((lane >> 3) & 3)) * 8;
    const size_t off0 = (size_t)(w * 16 + (lane >> 2)) * D_DIM + cl8;
    const short* Abase = X + (size_t)row0 * D_DIM;
    const short* Bbase = Wt + (size_t)by * 128 * D_DIM;

    const int swz3 = (l15 >> 1) & 3;

    f32x4 acc[4][2];
    #pragma unroll
    for (int i = 0; i < 4; ++i)
        #pragma unroll
        for (int j = 0; j < 2; ++j)
            acc[i][j] = (f32x4){0.f, 0.f, 0.f, 0.f};

    // prologue: stage k-tiles 0 and 1 (FIFO: A0,B0,A1,B1)
    glds16(Abase + off0,      AlS + 0*4096 + w*512);
    glds16(Bbase + off0,      BlS + 0*4096 + w*512);
    glds16(Abase + 32 + off0, AlS + 1*4096 + w*512);
    glds16(Bbase + 32 + off0, BlS + 1*4096 + w*512);

    const char* AlC = (const char*)AlS;
    const char* BlC = (const char*)BlS;

    int bC = 0, bS = 2;   // compute buffer (kt%3), stage target ((kt+2)%3)
    for (int kt = 0; kt < 32; ++kt) {
        if (kt < 30) {
            const int k2 = (kt + 2) * 32;
            glds16(Abase + k2 + off0, AlS + bS*4096 + w*512);
            glds16(Bbase + k2 + off0, BlS + bS*4096 + w*512);
            VMCNT(4);            // retire tile kt; kt+1, kt+2 stay in flight
        } else if (kt == 30) {
            VMCNT(2);
        } else {
            VMCNT(0);
        }
        __builtin_amdgcn_s_barrier();
        __builtin_amdgcn_sched_barrier(0);

        const int cbB = bC * 8192;   // byte offset of compute buffer
        bf16x8 af[4], bfr[2];
        #pragma unroll
        for (int mb = 0; mb < 4; ++mb)
            af[mb] = *(const bf16x8*)
                (AlC + cbB + ((wm*64 + mb*16 + l15)*32 + (g ^ swz3)*8) * 2);
        #pragma unroll
        for (int nb = 0; nb < 2; ++nb)
            bfr[nb] = *(const bf16x8*)
                (BlC + cbB + ((wn*32 + nb*16 + l15)*32 + (g ^ swz3)*8) * 2);
        #pragma unroll
        for (int mb = 0; mb < 4; ++mb)
            #pragma unroll
            for (int nb = 0; nb < 2; ++nb)
                acc[mb][nb] = __builtin_amdgcn_mfma_f32_16x16x32_bf16(
                    af[mb], bfr[nb], acc[mb][nb], 0, 0, 0);
        __builtin_amdgcn_sched_barrier(0);
        __builtin_amdgcn_s_barrier();

        bC = (bC == 2) ? 0 : bC + 1;
        bS = (bS == 2) ? 0 : bS + 1;
    }

    const float* bias = (region == 0) ? bq : (region == 1) ? bk : bv;
    const float scale = (region == 0) ? QSCALE : 1.0f;
    const int colL0 = (by & 7) * 128 + wn * 32;

    if (region < 2) {
        // per-wave bounce buffer overlays the (dead) Al region: [16][20] shorts
        short* Ttw = SH + w * 320;
        short* Out = (region == 0) ? Qo : Ko;
        #pragma unroll
        for (int mb = 0; mb < 4; ++mb)
            #pragma unroll
            for (int nb = 0; nb < 2; ++nb) {
                const float bvv = bias[colL0 + nb*16 + l15];
                #pragma unroll
                for (int r = 0; r < 4; ++r)
                    Ttw[(4*g + r)*20 + l15] = f2bf((acc[mb][nb][r] + bvv) * scale);
                bf16x4 t4 = *(const bf16x4*)&Ttw[l15*20 + 4*g];
                const int sg  = row0 + wm*64 + mb*16 + l15;
                const int bb  = sg >> 11, s = sg & 2047;
                const int cg  = colL0 + nb*16 + 4*g;
                const int n   = cg >> 6, hh = cg & 63;
                *(bf16x4*)&Out[(((size_t)(bb*N_HEADS + n)*S_DIM + s) << 6) + hh] = t4;
            }
    } else {
        #pragma unroll
        for (int mb = 0; mb < 4; ++mb)
            #pragma unroll
            for (int nb = 0; nb < 2; ++nb) {
                const int nhv = colL0 + nb*16 + l15;
                const float bvv = bias[nhv];
                bf16x4 t4;
                #pragma unroll
                for (int r = 0; r < 4; ++r)
                    t4[r] = f2bf(acc[mb][nb][r] + bvv);
                const int s4 = row0 + wm*64 + mb*16 + 4*g;
                const int bb = s4 >> 11, s = s4 & 2047;
                *(bf16x4*)&Vo[((size_t)(bb*NH + nhv) << 11) + s] = t4;
            }
    }
}

// ---------------------------------------------------------------------------
// Flash attention (r17-exact + T5 setprio around MFMA clusters): r13
// all-MFMA32 + T15 cross-tile pipeline. setprio(1) during QK and PV MFMA
// clusters lets MFMA-phase waves preempt co-resident blocks' VALU/staging
// phases (4 independent blocks/CU at different phases = T5's prerequisite).
// ---------------------------------------------------------------------------
__global__ __launch_bounds__(256)
void attn_mfma(const short* __restrict__ Qb, const short* __restrict__ Kb,
               const short* __restrict__ Vt,
               const unsigned long long* __restrict__ mp,
               float* __restrict__ out)
{
    __shared__ short Kl[2][4096];   // [buf][staged t-row * 64 + swizzled chunk]
    __shared__ short Vl[3][4096];   // [slot][h-row * 64 + swizzled chunk]

    const int tid  = threadIdx.x;
    const int lane = tid & 63, w = tid >> 6;
    const int g = lane >> 4, l15 = lane & 15;

    // XCD swizzle: each XCD gets 128 consecutive logical blocks = 4 heads
    const int lin = (blockIdx.x & 7) * 128 + (blockIdx.x >> 3);
    const int f0 = (lin & 31) << 6;
    const int n  = (lin >> 5) & 15;
    const int b  = lin >> 9;

    const short* Qbase = Qb + (size_t)(b*N_HEADS + n) * S_DIM * H_DIM;
    const short* Kbase = Kb + (size_t)(b*N_HEADS + n) * S_DIM * H_DIM;
    const short* Vbase = Vt + (size_t)(b*NH + n*H_DIM) * S_DIM;

    const int frow = f0 + w*16 + l15;        // this lane's f (fragment col)

    bf16x8 qf[2];
    #pragma unroll
    for (int hc = 0; hc < 2; ++hc)
        qf[hc] = *(const bf16x8*)&Qbase[(size_t)frow * H_DIM + hc*32 + 8*g];

    // ---- K staging with row permutation (r13-exact) ----
    const int e   = lane >> 3;               // staged row within 8-group
    const int cl8 = ((lane & 7) ^ e) * 8;    // chunk swizzle (key = s&7 = e)
    const int s32_0 = (w & 1) * 16 + e;      // staged local row, glds call 0
    const int s32_1 = s32_0 + 8;             //                  glds call 1
    const int i0 = s32_0 & 15, i1 = s32_1 & 15;
    const int t0loc = 8*(i0 >> 2) + (i0 & 3) + ((s32_0 >> 4) ? 4 : 0);
    const int t1loc = 8*(i1 >> 2) + (i1 & 3) + ((s32_1 >> 4) ? 4 : 0);
    const int grpw  = w >> 1;                // which 32-row group this wave stages
    const size_t kOff0 = (size_t)(grpw*32 + t0loc) * H_DIM + cl8;
    const size_t kOff1 = (size_t)(grpw*32 + t1loc) * H_DIM + cl8;
    // V staging: linear rows (h), r13-exact
    const int rk  = w * 16 + e;
    const size_t vOff0 = (size_t)rk * S_DIM + cl8;
    const size_t vOff1 = vOff0 + 8 * S_DIM;

    const unsigned long long* mrp = mp + ((size_t)(b*S_DIM + frow) << 5);

    const int swz7 = l15 & 7;
    const int g8 = 8 * g;
    const bf16x8 ones8 = {0x3F80, 0x3F80, 0x3F80, 0x3F80,
                          0x3F80, 0x3F80, 0x3F80, 0x3F80};

    // fragment byte-offsets (constant across t-loop; r13-exact)
    int koffA[4], koffB[4], voff32[2][4];
    #pragma unroll
    for (int tb = 0; tb < 4; ++tb) {
        koffA[tb] = ((tb*16 + l15)*64 + ((g    ) ^ swz7)*8) * 2;
        koffB[tb] = ((tb*16 + l15)*64 + ((4 + g) ^ swz7)*8) * 2;
    }
    #pragma unroll
    for (int grp = 0; grp < 2; ++grp)
        #pragma unroll
        for (int hb = 0; hb < 4; ++hb)
            voff32[grp][hb] = ((hb*16 + l15)*64 + ((grp*4 + g) ^ swz7)*8) * 2;

    f32x4 o2[4];     // O^T: row h = hb*16 + 4g + r, col f = l15
    f32x4 lacc;      // denominator (all rows equal)
    #pragma unroll
    for (int hb = 0; hb < 4; ++hb) o2[hb] = (f32x4){0.f, 0.f, 0.f, 0.f};
    lacc = (f32x4){0.f, 0.f, 0.f, 0.f};

    short* VlF = &Vl[0][0];

    // prologue: tile 0 -> K buf 0, V slot 0
    glds16(Kbase + kOff0, &Kl[0][w * 1024]);
    glds16(Kbase + kOff1, &Kl[0][w * 1024 + 512]);
    glds16(Vbase + vOff0, &VlF[0*4096 + w * 1024]);
    glds16(Vbase + vOff1, &VlF[0*4096 + w * 1024 + 512]);

    const char* KlB = (const char*)&Kl[0][0];
    const char* VlB = (const char*)&Vl[0][0];

    f32x4 sv[4];
    #pragma unroll
    for (int tb = 0; tb < 4; ++tb) sv[tb] = (f32x4){0.f, 0.f, 0.f, 0.f};
    unsigned long long mkP = 0, mkC = 0;
    int vsP = 2, vsC = 0, vsF = 1;   // prev / current / free(stage target)

    for (int tt = 0; tt <= 32; ++tt) {
        const int cur = tt & 1;
        const int cb  = cur << 13;           // K buffer byte offset

        if (tt < 32) mkC = mrp[tt];
        __builtin_amdgcn_sched_barrier(0);

        if (tt < 31) {
            const int t1 = (tt + 1) * 64;
            glds16(Kbase + (size_t)t1*H_DIM + kOff0, &Kl[cur^1][w*1024]);
            glds16(Kbase + (size_t)t1*H_DIM + kOff1, &Kl[cur^1][w*1024 + 512]);
            glds16(Vbase + t1 + vOff0, &VlF[vsF*4096 + w*1024]);
            glds16(Vbase + t1 + vOff1, &VlF[vsF*4096 + w*1024 + 512]);
            VMCNT(4);
        } else if (tt == 31) {
            VMCNT(0);
        }
        if (tt < 32) {
            __builtin_amdgcn_s_barrier();
            __builtin_amdgcn_sched_barrier(0);   // pin LDS reads after barrier
        }

        // ---- phase 1: softmax of tile tt-1 (consumes sv, mkP) ----
        bf16x8 P32g[2];
        if (tt > 0) {
            #pragma unroll
            for (int grp = 0; grp < 2; ++grp) {
                const f32x4 svA = sv[2*grp];       // t = grp*32 + 8g + r
                const f32x4 svB = sv[2*grp + 1];   // t = grp*32 + 8g + 4 + r
                const unsigned mbyte = (unsigned)(mkP >> (grp*32 + g8));
                float pA0 = (mbyte &   1u) ? __builtin_amdgcn_exp2f(svA[0]) : 0.f;
                float pA1 = (mbyte &   2u) ? __builtin_amdgcn_exp2f(svA[1]) : 0.f;
                float pA2 = (mbyte &   4u) ? __builtin_amdgcn_exp2f(svA[2]) : 0.f;
                float pA3 = (mbyte &   8u) ? __builtin_amdgcn_exp2f(svA[3]) : 0.f;
                float pB0 = (mbyte &  16u) ? __builtin_amdgcn_exp2f(svB[0]) : 0.f;
                float pB1 = (mbyte &  32u) ? __builtin_amdgcn_exp2f(svB[1]) : 0.f;
                float pB2 = (mbyte &  64u) ? __builtin_amdgcn_exp2f(svB[2]) : 0.f;
                float pB3 = (mbyte & 128u) ? __builtin_amdgcn_exp2f(svB[3]) : 0.f;
                unsigned u0, u1, u2, u3;
                asm("v_cvt_pk_bf16_f32 %0, %1, %2" : "=v"(u0) : "v"(pA0), "v"(pA1));
                asm("v_cvt_pk_bf16_f32 %0, %1, %2" : "=v"(u1) : "v"(pA2), "v"(pA3));
                asm("v_cvt_pk_bf16_f32 %0, %1, %2" : "=v"(u2) : "v"(pB0), "v"(pB1));
                asm("v_cvt_pk_bf16_f32 %0, %1, %2" : "=v"(u3) : "v"(pB2), "v"(pB3));
                union { unsigned u[4]; bf16x8 v; } pk;
                pk.u[0] = u0; pk.u[1] = u1; pk.u[2] = u2; pk.u[3] = u3;
                P32g[grp] = pk.v;                  // k = 8g + {0..7}
            }
        }

        // ---- phase 2: QK(tt) refills sv in place (setprio: MFMA cluster) ----
        if (tt < 32) {
            __builtin_amdgcn_s_setprio(1);
            #pragma unroll
            for (int tb = 0; tb < 4; ++tb) {
                bf16x8 kf0 = *(const bf16x8*)(KlB + cb + koffA[tb]);
                bf16x8 kf1 = *(const bf16x8*)(KlB + cb + koffB[tb]);
                const f32x4 z = (f32x4){0.f, 0.f, 0.f, 0.f};
                sv[tb] = __builtin_amdgcn_mfma_f32_16x16x32_bf16(kf0, qf[0], z, 0, 0, 0);
                sv[tb] = __builtin_amdgcn_mfma_f32_16x16x32_bf16(kf1, qf[1], sv[tb], 0, 0, 0);
            }
            __builtin_amdgcn_s_setprio(0);
        }

        // ---- phase 3: PV(tile tt-1) from V slot vsP (setprio cluster) ----
        if (tt > 0) {
            const int vb = vsP * 8192;   // V slot byte offset
            __builtin_amdgcn_s_setprio(1);
            #pragma unroll
            for (int grp = 0; grp < 2; ++grp) {
                #pragma unroll
                for (int hb = 0; hb < 4; ++hb) {
                    bf16x8 va = *(const bf16x8*)(VlB + vb + voff32[grp][hb]);
                    o2[hb] = __builtin_amdgcn_mfma_f32_16x16x32_bf16(
                        va, P32g[grp], o2[hb], 0, 0, 0);
                }
                lacc = __builtin_amdgcn_mfma_f32_16x16x32_bf16(
                    ones8, P32g[grp], lacc, 0, 0, 0);
            }
            __builtin_amdgcn_s_setprio(0);
        }

        __builtin_amdgcn_sched_barrier(0);   // pin reads BEFORE exit barrier
        if (tt < 32) __builtin_amdgcn_s_barrier();

        mkP = mkC;
        const int t_ = vsP; vsP = vsC; vsC = vsF; vsF = t_;
    }

    // ---- epilogue: normalize lane-locally, store f32x4 per (f, h-quad) ----
    {
        const float inv = 1.0f / lacc[0];
        float* orow = &out[((size_t)(b*S_DIM + frow) << 10) + (n << 6) + 4*g];
        #pragma unroll
        for (int hb = 0; hb < 4; ++hb) {
            f32x4 v = o2[hb] * inv;
            *(f32x4*)&orow[hb*16] = v;
        }
    }
}

extern "C" void kernel_launch(void* const* d_in, const int* in_sizes, int n_in,
                              void* d_out, int out_size, void* d_ws, size_t ws_size,
                              hipStream_t stream)
{
    const float* from = (const float*)d_in[0];
    const float* to   = (const float*)d_in[1];
    const int*   mask = (const int*)d_in[2];
    const float* wq   = (const float*)d_in[3];
    const float* bq   = (const float*)d_in[4];
    const float* wk   = (const float*)d_in[5];
    const float* bk   = (const float*)d_in[6];
    const float* wv   = (const float*)d_in[7];
    const float* bv   = (const float*)d_in[8];
    float* out = (float*)d_out;

    char* p = (char*)d_ws;
    const size_t sz_x   = (size_t)M_DIM * D_DIM * 2;
    const size_t sz_w   = (size_t)NH * D_DIM * 2;
    const size_t sz_qkv = (size_t)B_DIM * N_HEADS * S_DIM * H_DIM * 2;
    short* Fb  = (short*)p;            p += sz_x;
    short* Tbf = (short*)p;            p += sz_x;
    short* Wts = (short*)p;            p += 3 * sz_w;   // Q|K|V stacked
    short* Qw  = (short*)p;            p += sz_qkv;
    short* Kw  = (short*)p;            p += sz_qkv;
    short* Vw  = (short*)p;            p += sz_qkv;
    unsigned long long* mpk = (unsigned long long*)p;   // 1,048,576 B

    prep_fused<<<CVT_BLOCKS + WT_BLOCKS + MP_BLOCKS, 256, 0, stream>>>(
        from, to, Fb, Tbf, wq, wk, wv, Wts, mask, mpk);

    proj_mfma<<<768, 512, 0, stream>>>(Fb, Tbf, Wts, bq, bk, bv, Qw, Kw, Vw);

    attn_mfma<<<1024, 256, 0, stream>>>(Qw, Kw, Vw, mpk, out);
}